// Round 6
// baseline (1433.783 us; speedup 1.0000x reference)
//
#include <hip/hip_runtime.h>

#define NN 50000
#define DD 256
#define EE 800000
#define RR 5
#define HH 64
#define RN (RR * NN)
#define NBLK ((NN + 255) / 256)
#define NCHUNK 8
#define CW 32  // dims per chunk

typedef float v2f __attribute__((ext_vector_type(2)));

// ---- Q path ws layout (4-byte words) ----
// [0, RN)          cnt (int, [r*NN+d]) -> invc (float, in place)
// [Q_OFF, +RN+4)   off (int, [d*5+r], d-major) + sentinel at [RN]
// [Q_C, +RN)       c (float, [r*NN+s])
// [Q_G, +1280)     g
// [Q_W, +8)        w
// [Q_BSUM,+256)    per-block degree sums
// [Q_BBASE,+256)   exclusive block bases
// [Q_RANK)         rank (ushort, RR*EE)
// [Q_ESRC)         esrc (ushort, RR*EE)
// [Q_XH)           xh2 (bf16, [NCHUNK][NN][CW])
#define Q_OFF   (RN)
#define Q_C     (2 * RN + 4)
#define Q_G     (3 * RN + 4)
#define Q_W     (3 * RN + 1284)
#define Q_BSUM  (3 * RN + 1292)
#define Q_BBASE (3 * RN + 1548)
#define Q_RANK  (3 * RN + 1804)
#define Q_ESRC  (Q_RANK + RR * EE / 2)
#define Q_XH    (Q_ESRC + RR * EE / 2)
#define BYTES_Q ((size_t)(Q_XH + NCHUNK * NN * CW / 2) * 4)

// ---- round-2 CSR layout (fallback) ----
#define C2_OFF  (RN)
#define C2_CUR  (2 * RN)
#define C2_G    (3 * RN)
#define C2_W    (3 * RN + 1280)
#define C2_CTR  (3 * RN + 1288)
#define C2_ESRC (3 * RN + 1296)
#define BYTES_CSR2 ((size_t)(C2_ESRC + RR * EE) * 4)

__device__ inline unsigned short bf16rn(float f) {
    unsigned u = __float_as_uint(f);
    unsigned r = u + 0x7FFFu + ((u >> 16) & 1u);
    return (unsigned short)(r >> 16);
}

// ---------------- Q-path kernels ----------------

// count degrees AND record per-edge rank within its (r,d) bucket
__global__ __launch_bounds__(256) void deg2_kernel(const int* __restrict__ dst,
                                                   int* __restrict__ cnt,
                                                   unsigned short* __restrict__ rank) {
    int i = blockIdx.x * 256 + threadIdx.x;
    if (i < RR * EE) {
        int r = i / EE;
        int old = atomicAdd(&cnt[r * NN + dst[i]], 1);
        rank[i] = (unsigned short)old;
    }
}

__global__ __launch_bounds__(256) void bsum_kernel(const int* __restrict__ cnt,
                                                   int* __restrict__ bsum) {
    __shared__ int sh[256];
    const int t = threadIdx.x;
    const int d = blockIdx.x * 256 + t;
    int tot = 0;
    if (d < NN) {
        #pragma unroll
        for (int r = 0; r < RR; ++r) tot += cnt[r * NN + d];
    }
    sh[t] = tot;
    __syncthreads();
    for (int o = 128; o; o >>= 1) {
        if (t < o) sh[t] += sh[t + o];
        __syncthreads();
    }
    if (t == 0) bsum[blockIdx.x] = sh[0];
}

// parallel single-block scan over NBLK block sums; also writes off sentinel
__global__ __launch_bounds__(256) void bscan2_kernel(const int* __restrict__ bsum,
                                                     int* __restrict__ bbase,
                                                     int* __restrict__ off) {
    __shared__ int sh[256];
    const int t = threadIdx.x;
    int v = (t < NBLK) ? bsum[t] : 0;
    sh[t] = v;
    __syncthreads();
    for (int o = 1; o < 256; o <<= 1) {
        int p = (t >= o) ? sh[t - o] : 0;
        __syncthreads();
        sh[t] += p;
        __syncthreads();
    }
    if (t < NBLK) bbase[t] = sh[t] - v;
    if (t == 0) off[RN] = RR * EE;  // sentinel: end of last bucket
}

// per-d exclusive offsets (d-major) + invc in place of cnt; no cursor array
__global__ __launch_bounds__(256) void off3_kernel(int* __restrict__ cnt_invc,
                                                   const int* __restrict__ bbase,
                                                   int* __restrict__ off) {
    __shared__ int sh[256];
    const int t = threadIdx.x;
    const int d = blockIdx.x * 256 + t;
    int cc[RR];
    int tot = 0;
    if (d < NN) {
        #pragma unroll
        for (int r = 0; r < RR; ++r) {
            cc[r] = cnt_invc[r * NN + d];
            tot += cc[r];
        }
    }
    sh[t] = tot;
    __syncthreads();
    for (int o = 1; o < 256; o <<= 1) {
        int p = (t >= o) ? sh[t - o] : 0;
        __syncthreads();
        sh[t] += p;
        __syncthreads();
    }
    if (d < NN) {
        int base = bbase[blockIdx.x] + sh[t] - tot;
        float* invc = (float*)cnt_invc;
        #pragma unroll
        for (int r = 0; r < RR; ++r) {
            off[d * RR + r] = base;
            base += cc[r];
            invc[r * NN + d] = (cc[r] > 0) ? (1.0f / (float)cc[r]) : 0.0f;
        }
    }
}

// deterministic-slot fill (no cursor atomics) + fused c accumulation
__global__ __launch_bounds__(256) void fill3_kernel(const int* __restrict__ src,
                                                    const int* __restrict__ dst,
                                                    const unsigned short* __restrict__ rank,
                                                    const int* __restrict__ off,
                                                    unsigned short* __restrict__ esrc,
                                                    const float* __restrict__ invc,
                                                    float* __restrict__ c) {
    int i = blockIdx.x * 256 + threadIdx.x;
    if (i < RR * EE) {
        int r = i / EE;
        int d = dst[i];
        int s = src[i];
        int slot = off[d * RR + r] + (int)rank[i];
        esrc[slot] = (unsigned short)s;
        unsafeAtomicAdd(&c[r * NN + s], invc[r * NN + d]);
    }
}

// g[r][dfeat] = sum_s c[r][s] * x[s][dfeat] — streams x exactly once
__global__ __launch_bounds__(256) void gmat_kernel(const float* __restrict__ x,
                                                   const float* __restrict__ c,
                                                   float* __restrict__ g) {
    const int wave = threadIdx.x >> 6;
    const int lane = threadIdx.x & 63;
    const int gw = blockIdx.x * 4 + wave;
    const int nw = gridDim.x * 4;
    float4 a0 = {0, 0, 0, 0}, a1 = {0, 0, 0, 0}, a2 = {0, 0, 0, 0},
           a3 = {0, 0, 0, 0}, a4 = {0, 0, 0, 0};
    for (int s = gw; s < NN; s += nw) {
        float4 v = ((const float4*)(x + (size_t)s * DD))[lane];
        float c0 = c[0 * NN + s], c1 = c[1 * NN + s], c2 = c[2 * NN + s],
              c3 = c[3 * NN + s], c4 = c[4 * NN + s];
        a0.x += c0 * v.x; a0.y += c0 * v.y; a0.z += c0 * v.z; a0.w += c0 * v.w;
        a1.x += c1 * v.x; a1.y += c1 * v.y; a1.z += c1 * v.z; a1.w += c1 * v.w;
        a2.x += c2 * v.x; a2.y += c2 * v.y; a2.z += c2 * v.z; a2.w += c2 * v.w;
        a3.x += c3 * v.x; a3.y += c3 * v.y; a3.z += c3 * v.z; a3.w += c3 * v.w;
        a4.x += c4 * v.x; a4.y += c4 * v.y; a4.z += c4 * v.z; a4.w += c4 * v.w;
    }
    float4 acc[5] = {a0, a1, a2, a3, a4};
    #pragma unroll
    for (int r = 0; r < RR; ++r) {
        float* gr = g + r * DD + lane * 4;
        unsafeAtomicAdd(gr + 0, acc[r].x);
        unsafeAtomicAdd(gr + 1, acc[r].y);
        unsafeAtomicAdd(gr + 2, acc[r].z);
        unsafeAtomicAdd(gr + 3, acc[r].w);
    }
}

// 5 waves (one per relation), W1 staged in LDS
__global__ __launch_bounds__(320) void mlp5_kernel(const float* __restrict__ gsum,
                                                   const float* __restrict__ W1,
                                                   const float* __restrict__ b1,
                                                   const float* __restrict__ gamma,
                                                   const float* __restrict__ beta,
                                                   const float* __restrict__ W2,
                                                   const float* __restrict__ b2,
                                                   const float* __restrict__ attn_bias,
                                                   float* __restrict__ w) {
    __shared__ float w1s[DD * HH];
    __shared__ float gss[RR][DD];
    const int tid = threadIdx.x;
    for (int k = tid; k < DD * HH; k += 320) w1s[k] = W1[k];
    const int r = tid >> 6;
    const int t = tid & 63;
    for (int d = t; d < DD; d += 64) gss[r][d] = gsum[r * DD + d] * (1.0f / (float)NN);
    __syncthreads();
    float h = b1[t];
    for (int d = 0; d < DD; ++d) h += gss[r][d] * w1s[d * HH + t];
    float mu = h;
    #pragma unroll
    for (int o = 32; o; o >>= 1) mu += __shfl_xor(mu, o, 64);
    mu *= (1.0f / 64.0f);
    float cc = h - mu;
    float var = cc * cc;
    #pragma unroll
    for (int o = 32; o; o >>= 1) var += __shfl_xor(var, o, 64);
    var *= (1.0f / 64.0f);
    float hn = cc * rsqrtf(var + 1e-5f) * gamma[t] + beta[t];
    hn = fmaxf(hn, 0.0f);
    float sc = hn * W2[t];
    #pragma unroll
    for (int o = 32; o; o >>= 1) sc += __shfl_xor(sc, o, 64);
    if (t == 0) {
        float s = sc + b2[0] + attn_bias[r];
        float ww = 2.0f / (1.0f + expf(-s * 0.5f));
        ww = fminf(fmaxf(ww, 0.05f), 2.0f);
        w[r] = ww;
    }
}

// x (f32) -> chunk-major bf16 table xh2[chunk][s][CW]
__global__ __launch_bounds__(256) void xcvt2_kernel(const float* __restrict__ x,
                                                    unsigned short* __restrict__ xh2) {
    int i = blockIdx.x * 256 + threadIdx.x;
    if (i < NN * DD / 4) {
        int srow = i >> 6;     // 64 float4-quads per row
        int q4 = i & 63;
        float4 v = ((const float4*)x)[i];
        int chunk = q4 >> 3;   // 8 quads (32 dims) per chunk
        int pos = q4 & 7;
        ushort4 q;
        q.x = bf16rn(v.x); q.y = bf16rn(v.y); q.z = bf16rn(v.z); q.w = bf16rn(v.w);
        *(ushort4*)(xh2 + ((size_t)chunk * NN + srow) * CW + pos * 4) = q;
    }
}

// chunked pull: wave per node, 4 edge-groups x 16 lanes x 2 dims; L2-resident chunk table
__global__ __launch_bounds__(256) void pullc_kernel(const unsigned short* __restrict__ xh2,
                                                    const unsigned short* __restrict__ esrc,
                                                    const int* __restrict__ off,
                                                    const float* __restrict__ invc,
                                                    const float* __restrict__ w,
                                                    float* __restrict__ out,
                                                    int chunk) {
    const int node = blockIdx.x * 4 + (threadIdx.x >> 6);
    if (node >= NN) return;
    const int lane = threadIdx.x & 63;
    const int grp = lane >> 4;
    const int sl = lane & 15;
    const ushort2* __restrict__ xc =
        (const ushort2*)(xh2 + (size_t)chunk * NN * CW);
    float ax = 0.0f, ay = 0.0f;
    #pragma unroll
    for (int r = 0; r < RR; ++r) {
        const int idx = node * RR + r;
        const int b = __builtin_amdgcn_readfirstlane(off[idx]);
        const int e_ = __builtin_amdgcn_readfirstlane(off[idx + 1]);
        const float coef = w[r] * invc[r * NN + node];
        float tx = 0.0f, ty = 0.0f;
        for (int e = b + grp; e < e_; e += 4) {
            int s = (int)__builtin_nontemporal_load(&esrc[e]);
            ushort2 q = xc[s * 16 + sl];
            tx += __uint_as_float((unsigned)q.x << 16);
            ty += __uint_as_float((unsigned)q.y << 16);
        }
        ax += coef * tx;
        ay += coef * ty;
    }
    ax += __shfl_xor(ax, 16, 64); ax += __shfl_xor(ax, 32, 64);
    ay += __shfl_xor(ay, 16, 64); ay += __shfl_xor(ay, 32, 64);
    if (grp == 0) {
        v2f v = {ax, ay};
        __builtin_nontemporal_store(
            v, (v2f*)(out + (size_t)node * DD + chunk * CW + sl * 2));
    }
}

// ---------------- fallback kernels ----------------
__global__ __launch_bounds__(256) void deg_kernel(const int* __restrict__ dst,
                                                  int* __restrict__ cnt) {
    int i = blockIdx.x * 256 + threadIdx.x;
    if (i < RR * EE) {
        int r = i / EE;
        atomicAdd(&cnt[r * NN + dst[i]], 1);
    }
}

__global__ __launch_bounds__(256) void off_kernel(int* cnt, int* __restrict__ off,
                                                  int* __restrict__ cur,
                                                  int* __restrict__ ctr, float* invc) {
    int i = blockIdx.x * 256 + threadIdx.x;
    if (i < RN) {
        int cv = cnt[i];
        int o = atomicAdd(ctr, cv);
        off[i] = o;
        cur[i] = o;
        invc[i] = (cv > 0) ? (1.0f / (float)cv) : 0.0f;
    }
}

__global__ __launch_bounds__(256) void fill_kernel(const int* __restrict__ src,
                                                   const int* __restrict__ dst,
                                                   int* __restrict__ cur,
                                                   int* __restrict__ esrc) {
    int i = blockIdx.x * 256 + threadIdx.x;
    if (i < RR * EE) {
        int r = i / EE;
        int slot = atomicAdd(&cur[r * NN + dst[i]], 1);
        esrc[slot] = src[i];
    }
}

__global__ __launch_bounds__(256) void g_kernel(const float* __restrict__ x,
                                                const int* __restrict__ src,
                                                const int* __restrict__ dst,
                                                const float* __restrict__ invc,
                                                float* __restrict__ g) {
    const int r = blockIdx.y;
    const int wave = threadIdx.x >> 6;
    const int lane = threadIdx.x & 63;
    const int gw = blockIdx.x * 4 + wave;
    const int nw = gridDim.x * 4;
    const int* __restrict__ srcR = src + r * EE;
    const int* __restrict__ dstR = dst + r * EE;
    const float* __restrict__ invcR = invc + r * NN;
    float4 acc = {0, 0, 0, 0};
    for (int e = gw; e < EE; e += nw) {
        int eu = __builtin_amdgcn_readfirstlane(e);
        int s = srcR[eu];
        int dn = dstR[eu];
        float ic = invcR[dn];
        float4 v = ((const float4*)(x + (size_t)s * DD))[lane];
        acc.x += v.x * ic; acc.y += v.y * ic; acc.z += v.z * ic; acc.w += v.w * ic;
    }
    float* gr = g + r * DD + lane * 4;
    unsafeAtomicAdd(gr + 0, acc.x);
    unsafeAtomicAdd(gr + 1, acc.y);
    unsafeAtomicAdd(gr + 2, acc.z);
    unsafeAtomicAdd(gr + 3, acc.w);
}

__global__ __launch_bounds__(256) void out_pull_kernel(const float* __restrict__ x,
                                                       const int* __restrict__ esrc,
                                                       const int* __restrict__ off,
                                                       const int* __restrict__ endv,
                                                       const float* __restrict__ invc,
                                                       const float* __restrict__ w,
                                                       float* __restrict__ out) {
    const int node = blockIdx.x * 4 + (threadIdx.x >> 6);
    if (node >= NN) return;
    const int lane = threadIdx.x & 63;
    float4 acc = {0, 0, 0, 0};
    #pragma unroll
    for (int r = 0; r < RR; ++r) {
        const int idx = r * NN + node;
        const int b = __builtin_amdgcn_readfirstlane(off[idx]);
        const int e_ = __builtin_amdgcn_readfirstlane(endv[idx]);
        const float coef = w[r] * invc[idx];
        float4 t = {0, 0, 0, 0};
        for (int e = b; e < e_; ++e) {
            int s = __builtin_amdgcn_readfirstlane(esrc[e]);
            float4 v = ((const float4*)(x + (size_t)s * DD))[lane];
            t.x += v.x; t.y += v.y; t.z += v.z; t.w += v.w;
        }
        acc.x += coef * t.x; acc.y += coef * t.y;
        acc.z += coef * t.z; acc.w += coef * t.w;
    }
    ((float4*)(out + (size_t)node * DD))[lane] = acc;
}

__global__ __launch_bounds__(256) void invcnt_kernel(float* __restrict__ c) {
    int i = blockIdx.x * 256 + threadIdx.x;
    if (i < RN) {
        int v = ((const int*)c)[i];
        c[i] = (v > 0) ? (1.0f / (float)v) : 0.0f;
    }
}

__global__ __launch_bounds__(256) void out_scatter_kernel(const float* __restrict__ x,
                                                          const int* __restrict__ src,
                                                          const int* __restrict__ dst,
                                                          const float* __restrict__ invc,
                                                          const float* __restrict__ w,
                                                          float* __restrict__ out) {
    const int r = blockIdx.y;
    const float wr = w[r];
    const int wave = threadIdx.x >> 6;
    const int lane = threadIdx.x & 63;
    const int gw = blockIdx.x * 4 + wave;
    const int nw = gridDim.x * 4;
    const int* __restrict__ srcR = src + r * EE;
    const int* __restrict__ dstR = dst + r * EE;
    const float* __restrict__ invcR = invc + r * NN;
    for (int e = gw; e < EE; e += nw) {
        int eu = __builtin_amdgcn_readfirstlane(e);
        int s = srcR[eu];
        int dn = dstR[eu];
        float coef = wr * invcR[dn];
        float4 v = ((const float4*)(x + (size_t)s * DD))[lane];
        float* o = out + (size_t)dn * DD + lane * 4;
        unsafeAtomicAdd(o + 0, v.x * coef);
        unsafeAtomicAdd(o + 1, v.y * coef);
        unsafeAtomicAdd(o + 2, v.z * coef);
        unsafeAtomicAdd(o + 3, v.w * coef);
    }
}

extern "C" void kernel_launch(void* const* d_in, const int* in_sizes, int n_in,
                              void* d_out, int out_size, void* d_ws, size_t ws_size,
                              hipStream_t stream) {
    const float* x = (const float*)d_in[0];
    const int* src = (const int*)d_in[1];
    const int* dst = (const int*)d_in[2];
    const float* W1 = (const float*)d_in[3];
    const float* b1 = (const float*)d_in[4];
    const float* gamma = (const float*)d_in[5];
    const float* beta = (const float*)d_in[6];
    const float* W2 = (const float*)d_in[7];
    const float* b2 = (const float*)d_in[8];
    const float* attn_bias = (const float*)d_in[9];
    float* out = (float*)d_out;
    float* ws = (float*)d_ws;

    const int EDGE_GRID = (RR * EE + 255) / 256;
    const int RN_GRID = (RN + 255) / 256;

    if (ws_size >= BYTES_Q) {
        int* cnt = (int*)ws;
        float* invc = ws;
        int* off = (int*)ws + Q_OFF;
        float* c = ws + Q_C;
        float* g = ws + Q_G;
        float* w = ws + Q_W;
        int* bsum = (int*)ws + Q_BSUM;
        int* bbase = (int*)ws + Q_BBASE;
        unsigned short* rank = (unsigned short*)((int*)ws + Q_RANK);
        unsigned short* esrc = (unsigned short*)((int*)ws + Q_ESRC);
        unsigned short* xh2 = (unsigned short*)((int*)ws + Q_XH);

        hipMemsetAsync(cnt, 0, (size_t)RN * 4, stream);
        hipMemsetAsync(c, 0, (size_t)(RN + 1288) * 4, stream);  // c, g, w

        xcvt2_kernel<<<(NN * DD / 4 + 255) / 256, 256, 0, stream>>>(x, xh2);
        deg2_kernel<<<EDGE_GRID, 256, 0, stream>>>(dst, cnt, rank);
        bsum_kernel<<<NBLK, 256, 0, stream>>>(cnt, bsum);
        bscan2_kernel<<<1, 256, 0, stream>>>(bsum, bbase, off);
        off3_kernel<<<NBLK, 256, 0, stream>>>(cnt, bbase, off);
        fill3_kernel<<<EDGE_GRID, 256, 0, stream>>>(src, dst, rank, off, esrc, invc, c);
        gmat_kernel<<<128, 256, 0, stream>>>(x, c, g);
        mlp5_kernel<<<1, 320, 0, stream>>>(g, W1, b1, gamma, beta, W2, b2, attn_bias, w);
        for (int chunk = 0; chunk < NCHUNK; ++chunk)
            pullc_kernel<<<(NN + 3) / 4, 256, 0, stream>>>(xh2, esrc, off, invc, w,
                                                           out, chunk);
    } else if (ws_size >= BYTES_CSR2) {
        int* cnt = (int*)ws;
        float* invc = ws;
        int* off = (int*)ws + C2_OFF;
        int* cur = (int*)ws + C2_CUR;
        float* g = ws + C2_G;
        float* w = ws + C2_W;
        int* ctr = (int*)ws + C2_CTR;
        int* esrc = (int*)ws + C2_ESRC;

        hipMemsetAsync(cnt, 0, (size_t)RN * 4, stream);
        hipMemsetAsync(g, 0, (size_t)1296 * 4, stream);

        deg_kernel<<<EDGE_GRID, 256, 0, stream>>>(dst, cnt);
        off_kernel<<<RN_GRID, 256, 0, stream>>>(cnt, off, cur, ctr, invc);
        fill_kernel<<<EDGE_GRID, 256, 0, stream>>>(src, dst, cur, esrc);
        g_kernel<<<dim3(512, RR), 256, 0, stream>>>(x, src, dst, invc, g);
        mlp5_kernel<<<1, 320, 0, stream>>>(g, W1, b1, gamma, beta, W2, b2, attn_bias, w);
        out_pull_kernel<<<(NN + 3) / 4, 256, 0, stream>>>(x, esrc, off, cur, invc, w,
                                                          out);
    } else {
        float* cnt = ws;
        float* g = ws + RN;
        float* w = ws + RN + RR * DD;
        hipMemsetAsync(ws, 0, (size_t)(RN + RR * DD + RR) * 4, stream);
        hipMemsetAsync(d_out, 0, (size_t)NN * DD * 4, stream);
        deg_kernel<<<EDGE_GRID, 256, 0, stream>>>(dst, (int*)cnt);
        invcnt_kernel<<<RN_GRID, 256, 0, stream>>>(cnt);
        g_kernel<<<dim3(512, RR), 256, 0, stream>>>(x, src, dst, cnt, g);
        mlp5_kernel<<<1, 320, 0, stream>>>(g, W1, b1, gamma, beta, W2, b2, attn_bias, w);
        out_scatter_kernel<<<dim3(512, RR), 256, 0, stream>>>(x, src, dst, cnt, w, out);
    }
}

// Round 7
// 1006.128 us; speedup vs baseline: 1.4250x; 1.4250x over previous
//
#include <hip/hip_runtime.h>

#define NN 50000
#define DD 256
#define EE 800000
#define RR 5
#define HH 64
#define RN (RR * NN)
#define NBLK ((NN + 255) / 256)

typedef float v4f __attribute__((ext_vector_type(4)));

// ---- Q path ws layout (4-byte words) ----
// [0, RN)          cnt (int, [r*NN+d]) -> invc (float, in place)
// [Q_OFF, +RN+4)   off (int, [d*5+r], d-major) + sentinel at [RN]
// [Q_C, +RN)       c (float, [r*NN+s])
// [Q_G, +1280)     g
// [Q_W, +8)        w
// [Q_BSUM,+256)    per-block degree sums
// [Q_BBASE,+256)   exclusive block bases
// [Q_RANK)         rank (ushort, RR*EE)
// [Q_ESRC)         esrc (ushort, RR*EE)
// [Q_XH)           xh (bf16, row-major [NN][DD])
#define Q_OFF   (RN)
#define Q_C     (2 * RN + 4)
#define Q_G     (3 * RN + 4)
#define Q_W     (3 * RN + 1284)
#define Q_BSUM  (3 * RN + 1292)
#define Q_BBASE (3 * RN + 1548)
#define Q_RANK  (3 * RN + 1804)
#define Q_ESRC  (Q_RANK + RR * EE / 2)
#define Q_XH    (Q_ESRC + RR * EE / 2)
#define BYTES_Q ((size_t)(Q_XH + NN * DD / 2) * 4)

// ---- round-2 CSR layout (fallback) ----
#define C2_OFF  (RN)
#define C2_CUR  (2 * RN)
#define C2_G    (3 * RN)
#define C2_W    (3 * RN + 1280)
#define C2_CTR  (3 * RN + 1288)
#define C2_ESRC (3 * RN + 1296)
#define BYTES_CSR2 ((size_t)(C2_ESRC + RR * EE) * 4)

__device__ inline unsigned short bf16rn(float f) {
    unsigned u = __float_as_uint(f);
    unsigned r = u + 0x7FFFu + ((u >> 16) & 1u);
    return (unsigned short)(r >> 16);
}

// ---------------- Q-path kernels ----------------

// count degrees AND record per-edge rank within its (r,d) bucket
__global__ __launch_bounds__(256) void deg2_kernel(const int* __restrict__ dst,
                                                   int* __restrict__ cnt,
                                                   unsigned short* __restrict__ rank) {
    int i = blockIdx.x * 256 + threadIdx.x;
    if (i < RR * EE) {
        int r = i / EE;
        int d = __builtin_nontemporal_load(&dst[i]);
        int old = atomicAdd(&cnt[r * NN + d], 1);
        __builtin_nontemporal_store((unsigned short)old, &rank[i]);
    }
}

__global__ __launch_bounds__(256) void bsum_kernel(const int* __restrict__ cnt,
                                                   int* __restrict__ bsum) {
    __shared__ int sh[256];
    const int t = threadIdx.x;
    const int d = blockIdx.x * 256 + t;
    int tot = 0;
    if (d < NN) {
        #pragma unroll
        for (int r = 0; r < RR; ++r) tot += cnt[r * NN + d];
    }
    sh[t] = tot;
    __syncthreads();
    for (int o = 128; o; o >>= 1) {
        if (t < o) sh[t] += sh[t + o];
        __syncthreads();
    }
    if (t == 0) bsum[blockIdx.x] = sh[0];
}

// parallel single-block scan over NBLK block sums; writes off sentinel
__global__ __launch_bounds__(256) void bscan2_kernel(const int* __restrict__ bsum,
                                                     int* __restrict__ bbase,
                                                     int* __restrict__ off) {
    __shared__ int sh[256];
    const int t = threadIdx.x;
    int v = (t < NBLK) ? bsum[t] : 0;
    sh[t] = v;
    __syncthreads();
    for (int o = 1; o < 256; o <<= 1) {
        int p = (t >= o) ? sh[t - o] : 0;
        __syncthreads();
        sh[t] += p;
        __syncthreads();
    }
    if (t < NBLK) bbase[t] = sh[t] - v;
    if (t == 0) off[RN] = RR * EE;  // sentinel: end of last bucket
}

// per-d exclusive offsets (d-major) + invc in place of cnt
__global__ __launch_bounds__(256) void off3_kernel(int* __restrict__ cnt_invc,
                                                   const int* __restrict__ bbase,
                                                   int* __restrict__ off) {
    __shared__ int sh[256];
    const int t = threadIdx.x;
    const int d = blockIdx.x * 256 + t;
    int cc[RR];
    int tot = 0;
    if (d < NN) {
        #pragma unroll
        for (int r = 0; r < RR; ++r) {
            cc[r] = cnt_invc[r * NN + d];
            tot += cc[r];
        }
    }
    sh[t] = tot;
    __syncthreads();
    for (int o = 1; o < 256; o <<= 1) {
        int p = (t >= o) ? sh[t - o] : 0;
        __syncthreads();
        sh[t] += p;
        __syncthreads();
    }
    if (d < NN) {
        int base = bbase[blockIdx.x] + sh[t] - tot;
        float* invc = (float*)cnt_invc;
        #pragma unroll
        for (int r = 0; r < RR; ++r) {
            off[d * RR + r] = base;
            base += cc[r];
            invc[r * NN + d] = (cc[r] > 0) ? (1.0f / (float)cc[r]) : 0.0f;
        }
    }
}

// deterministic-slot fill, dst-range-blocked so active esrc window fits an XCD L2.
// c-atomics done only in the WITH_C pass (all edges, unconditioned).
template <bool WITH_C>
__global__ __launch_bounds__(256) void fill4_kernel(const int* __restrict__ src,
                                                    const int* __restrict__ dst,
                                                    const unsigned short* __restrict__ rank,
                                                    const int* __restrict__ off,
                                                    unsigned short* __restrict__ esrc,
                                                    const float* __restrict__ invc,
                                                    float* __restrict__ c,
                                                    int dlo, int dhi) {
    int i = blockIdx.x * 256 + threadIdx.x;
    if (i < RR * EE) {
        int r = i / EE;
        int d = __builtin_nontemporal_load(&dst[i]);
        if constexpr (WITH_C) {
            int s = __builtin_nontemporal_load(&src[i]);
            unsafeAtomicAdd(&c[r * NN + s], invc[r * NN + d]);
            if (d >= dlo && d < dhi) {
                int slot = off[d * RR + r] +
                           (int)__builtin_nontemporal_load(&rank[i]);
                esrc[slot] = (unsigned short)s;
            }
        } else {
            if (d >= dlo && d < dhi) {
                int s = __builtin_nontemporal_load(&src[i]);
                int slot = off[d * RR + r] +
                           (int)__builtin_nontemporal_load(&rank[i]);
                esrc[slot] = (unsigned short)s;
            }
        }
    }
}

// g[r][dfeat] = sum_s c[r][s] * x[s][dfeat] — streams x exactly once
__global__ __launch_bounds__(256) void gmat_kernel(const float* __restrict__ x,
                                                   const float* __restrict__ c,
                                                   float* __restrict__ g) {
    const int wave = threadIdx.x >> 6;
    const int lane = threadIdx.x & 63;
    const int gw = blockIdx.x * 4 + wave;
    const int nw = gridDim.x * 4;
    float4 a0 = {0, 0, 0, 0}, a1 = {0, 0, 0, 0}, a2 = {0, 0, 0, 0},
           a3 = {0, 0, 0, 0}, a4 = {0, 0, 0, 0};
    for (int s = gw; s < NN; s += nw) {
        float4 v = ((const float4*)(x + (size_t)s * DD))[lane];
        float c0 = c[0 * NN + s], c1 = c[1 * NN + s], c2 = c[2 * NN + s],
              c3 = c[3 * NN + s], c4 = c[4 * NN + s];
        a0.x += c0 * v.x; a0.y += c0 * v.y; a0.z += c0 * v.z; a0.w += c0 * v.w;
        a1.x += c1 * v.x; a1.y += c1 * v.y; a1.z += c1 * v.z; a1.w += c1 * v.w;
        a2.x += c2 * v.x; a2.y += c2 * v.y; a2.z += c2 * v.z; a2.w += c2 * v.w;
        a3.x += c3 * v.x; a3.y += c3 * v.y; a3.z += c3 * v.z; a3.w += c3 * v.w;
        a4.x += c4 * v.x; a4.y += c4 * v.y; a4.z += c4 * v.z; a4.w += c4 * v.w;
    }
    float4 acc[5] = {a0, a1, a2, a3, a4};
    #pragma unroll
    for (int r = 0; r < RR; ++r) {
        float* gr = g + r * DD + lane * 4;
        unsafeAtomicAdd(gr + 0, acc[r].x);
        unsafeAtomicAdd(gr + 1, acc[r].y);
        unsafeAtomicAdd(gr + 2, acc[r].z);
        unsafeAtomicAdd(gr + 3, acc[r].w);
    }
}

// 5 waves (one per relation), W1 staged in LDS
__global__ __launch_bounds__(320) void mlp5_kernel(const float* __restrict__ gsum,
                                                   const float* __restrict__ W1,
                                                   const float* __restrict__ b1,
                                                   const float* __restrict__ gamma,
                                                   const float* __restrict__ beta,
                                                   const float* __restrict__ W2,
                                                   const float* __restrict__ b2,
                                                   const float* __restrict__ attn_bias,
                                                   float* __restrict__ w) {
    __shared__ float w1s[DD * HH];
    __shared__ float gss[RR][DD];
    const int tid = threadIdx.x;
    for (int k = tid; k < DD * HH; k += 320) w1s[k] = W1[k];
    const int r = tid >> 6;
    const int t = tid & 63;
    for (int d = t; d < DD; d += 64) gss[r][d] = gsum[r * DD + d] * (1.0f / (float)NN);
    __syncthreads();
    float h = b1[t];
    for (int d = 0; d < DD; ++d) h += gss[r][d] * w1s[d * HH + t];
    float mu = h;
    #pragma unroll
    for (int o = 32; o; o >>= 1) mu += __shfl_xor(mu, o, 64);
    mu *= (1.0f / 64.0f);
    float cc = h - mu;
    float var = cc * cc;
    #pragma unroll
    for (int o = 32; o; o >>= 1) var += __shfl_xor(var, o, 64);
    var *= (1.0f / 64.0f);
    float hn = cc * rsqrtf(var + 1e-5f) * gamma[t] + beta[t];
    hn = fmaxf(hn, 0.0f);
    float sc = hn * W2[t];
    #pragma unroll
    for (int o = 32; o; o >>= 1) sc += __shfl_xor(sc, o, 64);
    if (t == 0) {
        float s = sc + b2[0] + attn_bias[r];
        float ww = 2.0f / (1.0f + expf(-s * 0.5f));
        ww = fminf(fmaxf(ww, 0.05f), 2.0f);
        w[r] = ww;
    }
}

// x (f32) -> row-major bf16 table
__global__ __launch_bounds__(256) void xcvt_kernel(const float* __restrict__ x,
                                                   ushort4* __restrict__ xh) {
    int i = blockIdx.x * 256 + threadIdx.x;
    if (i < NN * DD / 4) {
        float4 v = ((const float4*)x)[i];
        ushort4 q;
        q.x = bf16rn(v.x); q.y = bf16rn(v.y); q.z = bf16rn(v.z); q.w = bf16rn(v.w);
        xh[i] = q;
    }
}

// merged-relation pull: wave per node, one contiguous edge loop over all 5 buckets,
// per-edge coef picked by scalar boundary compares; 8-deep gather unroll.
__global__ __launch_bounds__(256) void out_pull3_kernel(const ushort4* __restrict__ xh,
                                                        const unsigned short* __restrict__ esrc,
                                                        const int* __restrict__ off,
                                                        const float* __restrict__ invc,
                                                        const float* __restrict__ w,
                                                        float* __restrict__ out) {
    const int node = blockIdx.x * 4 + (threadIdx.x >> 6);
    if (node >= NN) return;
    const int lane = threadIdx.x & 63;

    const int b0 = __builtin_amdgcn_readfirstlane(off[node * RR + 0]);
    const int b1 = __builtin_amdgcn_readfirstlane(off[node * RR + 1]);
    const int b2 = __builtin_amdgcn_readfirstlane(off[node * RR + 2]);
    const int b3 = __builtin_amdgcn_readfirstlane(off[node * RR + 3]);
    const int b4 = __builtin_amdgcn_readfirstlane(off[node * RR + 4]);
    const int b5 = __builtin_amdgcn_readfirstlane(off[node * RR + 5]);  // sentinel-safe

    const float c0 = w[0] * invc[0 * NN + node];
    const float c1 = w[1] * invc[1 * NN + node];
    const float c2 = w[2] * invc[2 * NN + node];
    const float c3 = w[3] * invc[3 * NN + node];
    const float c4 = w[4] * invc[4 * NN + node];

    float4 acc = {0, 0, 0, 0};
    int e = b0;
    for (; e + 8 <= b5; e += 8) {
        float4 vv[8];
        float cf[8];
        #pragma unroll
        for (int j = 0; j < 8; ++j) {
            int ej = e + j;
            int s = __builtin_amdgcn_readfirstlane((int)esrc[ej]);
            ushort4 q = xh[(size_t)s * 64 + lane];
            vv[j].x = __uint_as_float((unsigned)q.x << 16);
            vv[j].y = __uint_as_float((unsigned)q.y << 16);
            vv[j].z = __uint_as_float((unsigned)q.z << 16);
            vv[j].w = __uint_as_float((unsigned)q.w << 16);
            cf[j] = (ej < b1) ? c0 : (ej < b2) ? c1 : (ej < b3) ? c2
                  : (ej < b4) ? c3 : c4;
        }
        #pragma unroll
        for (int j = 0; j < 8; ++j) {
            acc.x = fmaf(cf[j], vv[j].x, acc.x);
            acc.y = fmaf(cf[j], vv[j].y, acc.y);
            acc.z = fmaf(cf[j], vv[j].z, acc.z);
            acc.w = fmaf(cf[j], vv[j].w, acc.w);
        }
    }
    for (; e < b5; ++e) {
        int s = __builtin_amdgcn_readfirstlane((int)esrc[e]);
        ushort4 q = xh[(size_t)s * 64 + lane];
        float cf = (e < b1) ? c0 : (e < b2) ? c1 : (e < b3) ? c2
                 : (e < b4) ? c3 : c4;
        acc.x = fmaf(cf, __uint_as_float((unsigned)q.x << 16), acc.x);
        acc.y = fmaf(cf, __uint_as_float((unsigned)q.y << 16), acc.y);
        acc.z = fmaf(cf, __uint_as_float((unsigned)q.z << 16), acc.z);
        acc.w = fmaf(cf, __uint_as_float((unsigned)q.w << 16), acc.w);
    }
    v4f o = {acc.x, acc.y, acc.z, acc.w};
    __builtin_nontemporal_store(o, (v4f*)(out + (size_t)node * DD + lane * 4));
}

// ---------------- fallback kernels ----------------
__global__ __launch_bounds__(256) void deg_kernel(const int* __restrict__ dst,
                                                  int* __restrict__ cnt) {
    int i = blockIdx.x * 256 + threadIdx.x;
    if (i < RR * EE) {
        int r = i / EE;
        atomicAdd(&cnt[r * NN + dst[i]], 1);
    }
}

__global__ __launch_bounds__(256) void off_kernel(int* cnt, int* __restrict__ off,
                                                  int* __restrict__ cur,
                                                  int* __restrict__ ctr, float* invc) {
    int i = blockIdx.x * 256 + threadIdx.x;
    if (i < RN) {
        int cv = cnt[i];
        int o = atomicAdd(ctr, cv);
        off[i] = o;
        cur[i] = o;
        invc[i] = (cv > 0) ? (1.0f / (float)cv) : 0.0f;
    }
}

__global__ __launch_bounds__(256) void fill_kernel(const int* __restrict__ src,
                                                   const int* __restrict__ dst,
                                                   int* __restrict__ cur,
                                                   int* __restrict__ esrc) {
    int i = blockIdx.x * 256 + threadIdx.x;
    if (i < RR * EE) {
        int r = i / EE;
        int slot = atomicAdd(&cur[r * NN + dst[i]], 1);
        esrc[slot] = src[i];
    }
}

__global__ __launch_bounds__(256) void g_kernel(const float* __restrict__ x,
                                                const int* __restrict__ src,
                                                const int* __restrict__ dst,
                                                const float* __restrict__ invc,
                                                float* __restrict__ g) {
    const int r = blockIdx.y;
    const int wave = threadIdx.x >> 6;
    const int lane = threadIdx.x & 63;
    const int gw = blockIdx.x * 4 + wave;
    const int nw = gridDim.x * 4;
    const int* __restrict__ srcR = src + r * EE;
    const int* __restrict__ dstR = dst + r * EE;
    const float* __restrict__ invcR = invc + r * NN;
    float4 acc = {0, 0, 0, 0};
    for (int e = gw; e < EE; e += nw) {
        int eu = __builtin_amdgcn_readfirstlane(e);
        int s = srcR[eu];
        int dn = dstR[eu];
        float ic = invcR[dn];
        float4 v = ((const float4*)(x + (size_t)s * DD))[lane];
        acc.x += v.x * ic; acc.y += v.y * ic; acc.z += v.z * ic; acc.w += v.w * ic;
    }
    float* gr = g + r * DD + lane * 4;
    unsafeAtomicAdd(gr + 0, acc.x);
    unsafeAtomicAdd(gr + 1, acc.y);
    unsafeAtomicAdd(gr + 2, acc.z);
    unsafeAtomicAdd(gr + 3, acc.w);
}

__global__ __launch_bounds__(256) void out_pull_kernel(const float* __restrict__ x,
                                                       const int* __restrict__ esrc,
                                                       const int* __restrict__ off,
                                                       const int* __restrict__ endv,
                                                       const float* __restrict__ invc,
                                                       const float* __restrict__ w,
                                                       float* __restrict__ out) {
    const int node = blockIdx.x * 4 + (threadIdx.x >> 6);
    if (node >= NN) return;
    const int lane = threadIdx.x & 63;
    float4 acc = {0, 0, 0, 0};
    #pragma unroll
    for (int r = 0; r < RR; ++r) {
        const int idx = r * NN + node;
        const int b = __builtin_amdgcn_readfirstlane(off[idx]);
        const int e_ = __builtin_amdgcn_readfirstlane(endv[idx]);
        const float coef = w[r] * invc[idx];
        float4 t = {0, 0, 0, 0};
        for (int e = b; e < e_; ++e) {
            int s = __builtin_amdgcn_readfirstlane(esrc[e]);
            float4 v = ((const float4*)(x + (size_t)s * DD))[lane];
            t.x += v.x; t.y += v.y; t.z += v.z; t.w += v.w;
        }
        acc.x += coef * t.x; acc.y += coef * t.y;
        acc.z += coef * t.z; acc.w += coef * t.w;
    }
    ((float4*)(out + (size_t)node * DD))[lane] = acc;
}

__global__ __launch_bounds__(256) void invcnt_kernel(float* __restrict__ c) {
    int i = blockIdx.x * 256 + threadIdx.x;
    if (i < RN) {
        int v = ((const int*)c)[i];
        c[i] = (v > 0) ? (1.0f / (float)v) : 0.0f;
    }
}

__global__ __launch_bounds__(256) void out_scatter_kernel(const float* __restrict__ x,
                                                          const int* __restrict__ src,
                                                          const int* __restrict__ dst,
                                                          const float* __restrict__ invc,
                                                          const float* __restrict__ w,
                                                          float* __restrict__ out) {
    const int r = blockIdx.y;
    const float wr = w[r];
    const int wave = threadIdx.x >> 6;
    const int lane = threadIdx.x & 63;
    const int gw = blockIdx.x * 4 + wave;
    const int nw = gridDim.x * 4;
    const int* __restrict__ srcR = src + r * EE;
    const int* __restrict__ dstR = dst + r * EE;
    const float* __restrict__ invcR = invc + r * NN;
    for (int e = gw; e < EE; e += nw) {
        int eu = __builtin_amdgcn_readfirstlane(e);
        int s = srcR[eu];
        int dn = dstR[eu];
        float coef = wr * invcR[dn];
        float4 v = ((const float4*)(x + (size_t)s * DD))[lane];
        float* o = out + (size_t)dn * DD + lane * 4;
        unsafeAtomicAdd(o + 0, v.x * coef);
        unsafeAtomicAdd(o + 1, v.y * coef);
        unsafeAtomicAdd(o + 2, v.z * coef);
        unsafeAtomicAdd(o + 3, v.w * coef);
    }
}

extern "C" void kernel_launch(void* const* d_in, const int* in_sizes, int n_in,
                              void* d_out, int out_size, void* d_ws, size_t ws_size,
                              hipStream_t stream) {
    const float* x = (const float*)d_in[0];
    const int* src = (const int*)d_in[1];
    const int* dst = (const int*)d_in[2];
    const float* W1 = (const float*)d_in[3];
    const float* b1 = (const float*)d_in[4];
    const float* gamma = (const float*)d_in[5];
    const float* beta = (const float*)d_in[6];
    const float* W2 = (const float*)d_in[7];
    const float* b2 = (const float*)d_in[8];
    const float* attn_bias = (const float*)d_in[9];
    float* out = (float*)d_out;
    float* ws = (float*)d_ws;

    const int EDGE_GRID = (RR * EE + 255) / 256;
    const int RN_GRID = (RN + 255) / 256;

    if (ws_size >= BYTES_Q) {
        int* cnt = (int*)ws;
        float* invc = ws;
        int* off = (int*)ws + Q_OFF;
        float* c = ws + Q_C;
        float* g = ws + Q_G;
        float* w = ws + Q_W;
        int* bsum = (int*)ws + Q_BSUM;
        int* bbase = (int*)ws + Q_BBASE;
        unsigned short* rank = (unsigned short*)((int*)ws + Q_RANK);
        unsigned short* esrc = (unsigned short*)((int*)ws + Q_ESRC);
        ushort4* xh = (ushort4*)((int*)ws + Q_XH);

        hipMemsetAsync(cnt, 0, (size_t)RN * 4, stream);
        hipMemsetAsync(c, 0, (size_t)(RN + 1288) * 4, stream);  // c, g, w

        xcvt_kernel<<<(NN * DD / 4 + 255) / 256, 256, 0, stream>>>(x, xh);
        deg2_kernel<<<EDGE_GRID, 256, 0, stream>>>(dst, cnt, rank);
        bsum_kernel<<<NBLK, 256, 0, stream>>>(cnt, bsum);
        bscan2_kernel<<<1, 256, 0, stream>>>(bsum, bbase, off);
        off3_kernel<<<NBLK, 256, 0, stream>>>(cnt, bbase, off);
        fill4_kernel<true><<<EDGE_GRID, 256, 0, stream>>>(src, dst, rank, off, esrc,
                                                          invc, c, 0, NN / 2);
        fill4_kernel<false><<<EDGE_GRID, 256, 0, stream>>>(src, dst, rank, off, esrc,
                                                           invc, c, NN / 2, NN);
        gmat_kernel<<<128, 256, 0, stream>>>(x, c, g);
        mlp5_kernel<<<1, 320, 0, stream>>>(g, W1, b1, gamma, beta, W2, b2, attn_bias, w);
        out_pull3_kernel<<<(NN + 3) / 4, 256, 0, stream>>>(xh, esrc, off, invc, w, out);
    } else if (ws_size >= BYTES_CSR2) {
        int* cnt = (int*)ws;
        float* invc = ws;
        int* off = (int*)ws + C2_OFF;
        int* cur = (int*)ws + C2_CUR;
        float* g = ws + C2_G;
        float* w = ws + C2_W;
        int* ctr = (int*)ws + C2_CTR;
        int* esrc = (int*)ws + C2_ESRC;

        hipMemsetAsync(cnt, 0, (size_t)RN * 4, stream);
        hipMemsetAsync(g, 0, (size_t)1296 * 4, stream);

        deg_kernel<<<EDGE_GRID, 256, 0, stream>>>(dst, cnt);
        off_kernel<<<RN_GRID, 256, 0, stream>>>(cnt, off, cur, ctr, invc);
        fill_kernel<<<EDGE_GRID, 256, 0, stream>>>(src, dst, cur, esrc);
        g_kernel<<<dim3(512, RR), 256, 0, stream>>>(x, src, dst, invc, g);
        mlp5_kernel<<<1, 320, 0, stream>>>(g, W1, b1, gamma, beta, W2, b2, attn_bias, w);
        out_pull_kernel<<<(NN + 3) / 4, 256, 0, stream>>>(x, esrc, off, cur, invc, w,
                                                          out);
    } else {
        float* cnt = ws;
        float* g = ws + RN;
        float* w = ws + RN + RR * DD;
        hipMemsetAsync(ws, 0, (size_t)(RN + RR * DD + RR) * 4, stream);
        hipMemsetAsync(d_out, 0, (size_t)NN * DD * 4, stream);
        deg_kernel<<<EDGE_GRID, 256, 0, stream>>>(dst, (int*)cnt);
        invcnt_kernel<<<RN_GRID, 256, 0, stream>>>(cnt);
        g_kernel<<<dim3(512, RR), 256, 0, stream>>>(x, src, dst, cnt, g);
        mlp5_kernel<<<1, 320, 0, stream>>>(g, W1, b1, gamma, beta, W2, b2, attn_bias, w);
        out_scatter_kernel<<<dim3(512, RR), 256, 0, stream>>>(x, src, dst, cnt, w, out);
    }
}